// Round 1
// baseline (633.017 us; speedup 1.0000x reference)
//
#include <hip/hip_runtime.h>
#include <hip/hip_bf16.h>
#include <stdint.h>

// Problem constants
#define T_TOK 1024
#define D_DIM 2048
#define DFF   1024
#define NE    16
#define TOPK  6
#define KD    (NE * DFF)   // 16384

typedef float f32x4 __attribute__((ext_vector_type(4)));
typedef __bf16 bf16x8 __attribute__((ext_vector_type(8)));
typedef unsigned short u16x8 __attribute__((ext_vector_type(8)));

// RNE float -> bf16 (finite inputs only)
__device__ __forceinline__ unsigned short f2bf(float f) {
    union { float f; unsigned int u; } v; v.f = f;
    unsigned int x = v.u;
    unsigned int r = x + 0x7FFFu + ((x >> 16) & 1u);
    return (unsigned short)(r >> 16);
}

// ---------------- conversion kernels ----------------

__global__ void cvt_f32_bf16(const float* __restrict__ src,
                             unsigned short* __restrict__ dst, int n4) {
    int i = blockIdx.x * blockDim.x + threadIdx.x;
    int stride = gridDim.x * blockDim.x;
    for (; i < n4; i += stride) {
        float4 v = ((const float4*)src)[i];
        ushort4 o;
        o.x = f2bf(v.x); o.y = f2bf(v.y); o.z = f2bf(v.z); o.w = f2bf(v.w);
        ((ushort4*)dst)[i] = o;
    }
}

// w2 [E, D, DFF] f32  ->  wb2t [D, E*DFF] bf16
__global__ void cvt_w2_transpose(const float* __restrict__ w2,
                                 unsigned short* __restrict__ dst, int n4) {
    int i = blockIdx.x * blockDim.x + threadIdx.x;
    int stride = gridDim.x * blockDim.x;
    const int F4 = DFF / 4;
    for (; i < n4; i += stride) {
        int f4 = i % F4;
        int rest = i / F4;
        int d = rest % D_DIM;
        int e = rest / D_DIM;
        float4 v = ((const float4*)w2)[(size_t)(e * D_DIM + d) * F4 + f4];
        ushort4 o;
        o.x = f2bf(v.x); o.y = f2bf(v.y); o.z = f2bf(v.z); o.w = f2bf(v.w);
        ((ushort4*)dst)[(size_t)d * (KD / 4) + e * F4 + f4] = o;
    }
}

// cw[e*T + t] += rw[t,k] for each selected expert slot
__global__ void cw_scatter(const int* __restrict__ sel,
                           const float* __restrict__ rw,
                           float* __restrict__ cw) {
    int i = blockIdx.x * blockDim.x + threadIdx.x;
    if (i < T_TOK * TOPK) {
        int t = i / TOPK;
        int e = sel[i];
        atomicAdd(&cw[e * T_TOK + t], rw[i]);
    }
}

// ---------------- GEMM1: fused gate+up+SwiGLU ----------------
// For expert e: G = x @ w0e^T, U = x @ w1e^T (NT GEMM, K=D=2048)
// Hs[t, e*DFF+f] = silu(G*s0)*（U*s1) * cw[e,t] * s2[e]   (bf16)
// Tile 128x128, BK=64, 4 waves (2x2), dual accumulators.
__global__ __launch_bounds__(256, 2)
void gemm1_kernel(const unsigned short* __restrict__ xb,   // [T, D]
                  const unsigned short* __restrict__ wb0,  // [E, DFF, D]
                  const unsigned short* __restrict__ wb1,  // [E, DFF, D]
                  const float* __restrict__ cw,            // [E, T]
                  const float* __restrict__ s0,
                  const float* __restrict__ s1,
                  const float* __restrict__ s2,
                  unsigned short* __restrict__ hs)         // [T, KD]
{
    const int tf = blockIdx.x, tt = blockIdx.y, e = blockIdx.z;
    const int tid = threadIdx.x;
    const int lane = tid & 63, wid = tid >> 6;
    const int wm = wid >> 1, wn = wid & 1;
    const int quad = lane >> 4, l16 = lane & 15;

    __shared__ alignas(16) unsigned short sA [128 * 64];
    __shared__ alignas(16) unsigned short sB0[128 * 64];
    __shared__ alignas(16) unsigned short sB1[128 * 64];
    __shared__ float cws[128];

    if (tid < 128) cws[tid] = cw[e * T_TOK + tt * 128 + tid];

    const unsigned short* a_base  = xb  + (size_t)(tt * 128) * D_DIM;
    const unsigned short* b0_base = wb0 + ((size_t)e * DFF + tf * 128) * D_DIM;
    const unsigned short* b1_base = wb1 + ((size_t)e * DFF + tf * 128) * D_DIM;

    f32x4 accG[4][4], accU[4][4];
    const f32x4 zz = {0.f, 0.f, 0.f, 0.f};
#pragma unroll
    for (int mi = 0; mi < 4; ++mi)
#pragma unroll
        for (int ni = 0; ni < 4; ++ni) { accG[mi][ni] = zz; accU[mi][ni] = zz; }

    for (int k0 = 0; k0 < D_DIM; k0 += 64) {
        u16x8 rA[4], rB0[4], rB1[4];
#pragma unroll
        for (int it = 0; it < 4; ++it) {
            int c = it * 256 + tid;
            int row = c >> 3, col = c & 7;
            rA [it] = *(const u16x8*)(a_base  + (size_t)row * D_DIM + k0 + col * 8);
            rB0[it] = *(const u16x8*)(b0_base + (size_t)row * D_DIM + k0 + col * 8);
            rB1[it] = *(const u16x8*)(b1_base + (size_t)row * D_DIM + k0 + col * 8);
        }
        __syncthreads();   // previous K-step's compute done before LDS overwrite
#pragma unroll
        for (int it = 0; it < 4; ++it) {
            int c = it * 256 + tid;
            int row = c >> 3, col = c & 7;
            int cs = col ^ (row & 7);          // XOR swizzle: breaks pow2 stride
            *(u16x8*)(sA  + row * 64 + cs * 8) = rA [it];
            *(u16x8*)(sB0 + row * 64 + cs * 8) = rB0[it];
            *(u16x8*)(sB1 + row * 64 + cs * 8) = rB1[it];
        }
        __syncthreads();
#pragma unroll
        for (int kk = 0; kk < 2; ++kk) {
            bf16x8 af[4], b0f[4], b1f[4];
#pragma unroll
            for (int mi = 0; mi < 4; ++mi) {
                int row = wm * 64 + mi * 16 + l16;
                int cch = (kk * 4 + quad) ^ (row & 7);
                af[mi] = __builtin_bit_cast(bf16x8,
                         *(const u16x8*)(sA + row * 64 + cch * 8));
            }
#pragma unroll
            for (int ni = 0; ni < 4; ++ni) {
                int row = wn * 64 + ni * 16 + l16;
                int cch = (kk * 4 + quad) ^ (row & 7);
                b0f[ni] = __builtin_bit_cast(bf16x8,
                          *(const u16x8*)(sB0 + row * 64 + cch * 8));
                b1f[ni] = __builtin_bit_cast(bf16x8,
                          *(const u16x8*)(sB1 + row * 64 + cch * 8));
            }
#pragma unroll
            for (int mi = 0; mi < 4; ++mi)
#pragma unroll
                for (int ni = 0; ni < 4; ++ni) {
                    accG[mi][ni] = __builtin_amdgcn_mfma_f32_16x16x32_bf16(
                        af[mi], b0f[ni], accG[mi][ni], 0, 0, 0);
                    accU[mi][ni] = __builtin_amdgcn_mfma_f32_16x16x32_bf16(
                        af[mi], b1f[ni], accU[mi][ni], 0, 0, 0);
                }
        }
    }

    const float s0e = s0[e], s1e = s1[e], s2e = s2[e];
#pragma unroll
    for (int mi = 0; mi < 4; ++mi) {
#pragma unroll
        for (int reg = 0; reg < 4; ++reg) {
            int tl = wm * 64 + mi * 16 + quad * 4 + reg;   // C/D row = quad*4+reg
            float cwt = cws[tl] * s2e;
            size_t t = (size_t)(tt * 128 + tl);
#pragma unroll
            for (int ni = 0; ni < 4; ++ni) {
                float g = accG[mi][ni][reg] * s0e;
                float u = accU[mi][ni][reg] * s1e;
                float h = g / (1.f + __expf(-g)) * u;      // silu(g)*u
                float val = h * cwt;
                int fc = tf * 128 + wn * 64 + ni * 16 + l16;  // C/D col = lane&15
                hs[t * KD + e * DFF + fc] = f2bf(val);
            }
        }
    }
}

// ---------------- GEMM2: down projection, single NT GEMM K=16384 ----------------
// out[t,d] = sum_k Hs[t,k] * wb2t[d,k], split-K=4 into partials.
__global__ __launch_bounds__(256, 2)
void gemm2_kernel(const unsigned short* __restrict__ hsrc,  // [T, KD]
                  const unsigned short* __restrict__ wb2t,  // [D, KD]
                  float* __restrict__ part)                 // [4, T, D]
{
    const int td = blockIdx.x, tt = blockIdx.y, sp = blockIdx.z;
    const int tid = threadIdx.x;
    const int lane = tid & 63, wid = tid >> 6;
    const int wm = wid >> 1, wn = wid & 1;
    const int quad = lane >> 4, l16 = lane & 15;

    __shared__ alignas(16) unsigned short sA[128 * 64];
    __shared__ alignas(16) unsigned short sB[128 * 64];

    const unsigned short* a_base = hsrc + (size_t)(tt * 128) * KD;
    const unsigned short* b_base = wb2t + (size_t)(td * 128) * KD;

    f32x4 acc[4][4];
    const f32x4 zz = {0.f, 0.f, 0.f, 0.f};
#pragma unroll
    for (int mi = 0; mi < 4; ++mi)
#pragma unroll
        for (int ni = 0; ni < 4; ++ni) acc[mi][ni] = zz;

    const int kbeg = sp * (KD / 4);
    const int kend = kbeg + (KD / 4);
    for (int k0 = kbeg; k0 < kend; k0 += 64) {
        u16x8 rA[4], rB[4];
#pragma unroll
        for (int it = 0; it < 4; ++it) {
            int c = it * 256 + tid;
            int row = c >> 3, col = c & 7;
            rA[it] = *(const u16x8*)(a_base + (size_t)row * KD + k0 + col * 8);
            rB[it] = *(const u16x8*)(b_base + (size_t)row * KD + k0 + col * 8);
        }
        __syncthreads();
#pragma unroll
        for (int it = 0; it < 4; ++it) {
            int c = it * 256 + tid;
            int row = c >> 3, col = c & 7;
            int cs = col ^ (row & 7);
            *(u16x8*)(sA + row * 64 + cs * 8) = rA[it];
            *(u16x8*)(sB + row * 64 + cs * 8) = rB[it];
        }
        __syncthreads();
#pragma unroll
        for (int kk = 0; kk < 2; ++kk) {
            bf16x8 af[4], bf[4];
#pragma unroll
            for (int mi = 0; mi < 4; ++mi) {
                int row = wm * 64 + mi * 16 + l16;
                int cch = (kk * 4 + quad) ^ (row & 7);
                af[mi] = __builtin_bit_cast(bf16x8,
                         *(const u16x8*)(sA + row * 64 + cch * 8));
            }
#pragma unroll
            for (int ni = 0; ni < 4; ++ni) {
                int row = wn * 64 + ni * 16 + l16;
                int cch = (kk * 4 + quad) ^ (row & 7);
                bf[ni] = __builtin_bit_cast(bf16x8,
                         *(const u16x8*)(sB + row * 64 + cch * 8));
            }
#pragma unroll
            for (int mi = 0; mi < 4; ++mi)
#pragma unroll
                for (int ni = 0; ni < 4; ++ni)
                    acc[mi][ni] = __builtin_amdgcn_mfma_f32_16x16x32_bf16(
                        af[mi], bf[ni], acc[mi][ni], 0, 0, 0);
        }
    }

    float* pout = part + (size_t)sp * T_TOK * D_DIM;
#pragma unroll
    for (int mi = 0; mi < 4; ++mi)
#pragma unroll
        for (int reg = 0; reg < 4; ++reg) {
            int t = tt * 128 + wm * 64 + mi * 16 + quad * 4 + reg;
            size_t rowoff = (size_t)t * D_DIM;
#pragma unroll
            for (int ni = 0; ni < 4; ++ni) {
                int d = td * 128 + wn * 64 + ni * 16 + l16;
                pout[rowoff + d] = acc[mi][ni][reg];
            }
        }
}

__global__ void reduce4(const float* __restrict__ part, float* __restrict__ out, int n4) {
    int i = blockIdx.x * blockDim.x + threadIdx.x;
    int stride = gridDim.x * blockDim.x;
    const float4* p0 = (const float4*)(part);
    const float4* p1 = (const float4*)(part + (size_t)T_TOK * D_DIM);
    const float4* p2 = (const float4*)(part + (size_t)2 * T_TOK * D_DIM);
    const float4* p3 = (const float4*)(part + (size_t)3 * T_TOK * D_DIM);
    for (; i < n4; i += stride) {
        float4 a = p0[i], b = p1[i], c = p2[i], d = p3[i];
        float4 o;
        o.x = a.x + b.x + c.x + d.x;
        o.y = a.y + b.y + c.y + d.y;
        o.z = a.z + b.z + c.z + d.z;
        o.w = a.w + b.w + c.w + d.w;
        ((float4*)out)[i] = o;
    }
}

// ---------------- launch ----------------

extern "C" void kernel_launch(void* const* d_in, const int* in_sizes, int n_in,
                              void* d_out, int out_size, void* d_ws, size_t ws_size,
                              hipStream_t stream) {
    const float* x  = (const float*)d_in[0];
    const float* w0 = (const float*)d_in[1];
    const float* w1 = (const float*)d_in[2];
    const float* w2 = (const float*)d_in[3];
    const float* s0 = (const float*)d_in[4];
    const float* s1 = (const float*)d_in[5];
    const float* s2 = (const float*)d_in[6];
    const int*   sel = (const int*)d_in[7];
    const float* rw = (const float*)d_in[8];
    float* out = (float*)d_out;

    char* ws = (char*)d_ws;
    // region layout (peak ~172 MB, with reuse):
    constexpr size_t WB0_OFF  = 0;                    // 67,108,864  (later: WB2T)
    constexpr size_t WB1_OFF  = 67108864ull;          // 67,108,864  (later: PART 33.5MB)
    constexpr size_t HS_OFF   = 134217728ull;         // 33,554,432
    constexpr size_t XB_OFF   = 167772160ull;         //  4,194,304
    constexpr size_t CW_OFF   = 171966464ull;         //     65,536
    unsigned short* wb0  = (unsigned short*)(ws + WB0_OFF);
    unsigned short* wb1  = (unsigned short*)(ws + WB1_OFF);
    unsigned short* wb2t = (unsigned short*)(ws + WB0_OFF);   // reuse after gemm1
    float*          partb= (float*)        (ws + WB1_OFF);    // reuse after gemm1
    unsigned short* hsb  = (unsigned short*)(ws + HS_OFF);
    unsigned short* xb   = (unsigned short*)(ws + XB_OFF);
    float*          cw   = (float*)        (ws + CW_OFF);

    // 1. combine weights cw[E,T]
    hipMemsetAsync(cw, 0, NE * T_TOK * sizeof(float), stream);
    cw_scatter<<<(T_TOK * TOPK + 255) / 256, 256, 0, stream>>>(sel, rw, cw);

    // 2. fp32 -> bf16 conversions
    cvt_f32_bf16<<<2048, 256, 0, stream>>>(x, xb, T_TOK * D_DIM / 4);
    cvt_f32_bf16<<<4096, 256, 0, stream>>>(w0, wb0, NE * DFF * D_DIM / 4);
    cvt_f32_bf16<<<4096, 256, 0, stream>>>(w1, wb1, NE * DFF * D_DIM / 4);

    // 3. fused gate/up/SwiGLU -> Hs (cw*s2 folded in)
    gemm1_kernel<<<dim3(DFF / 128, T_TOK / 128, NE), 256, 0, stream>>>(
        xb, wb0, wb1, cw, s0, s1, s2, hsb);

    // 4. w2 -> [D, E*DFF] bf16 (overwrites wb0 region; stream-serial so safe)
    cvt_w2_transpose<<<4096, 256, 0, stream>>>(w2, wb2t, NE * D_DIM * DFF / 4);

    // 5. down projection, one NT GEMM K=16384, split-K=4 (partials into old wb1)
    gemm2_kernel<<<dim3(D_DIM / 128, T_TOK / 128, 4), 256, 0, stream>>>(
        hsb, wb2t, partb);

    // 6. reduce partials -> out
    reduce4<<<2048, 256, 0, stream>>>(partb, out, T_TOK * D_DIM / 4);
}

// Round 2
// 558.643 us; speedup vs baseline: 1.1331x; 1.1331x over previous
//
#include <hip/hip_runtime.h>
#include <hip/hip_bf16.h>
#include <stdint.h>

// Problem constants
#define T_TOK 1024
#define D_DIM 2048
#define DFF   1024
#define NE    16
#define TOPK  6

typedef float f32x4 __attribute__((ext_vector_type(4)));
typedef __bf16 bf16x8 __attribute__((ext_vector_type(8)));
typedef unsigned short u16x8 __attribute__((ext_vector_type(8)));

// RNE float -> bf16 (epilogue only; finite inputs)
__device__ __forceinline__ unsigned short f2bf(float f) {
    union { float f; unsigned int u; } v; v.f = f;
    unsigned int x = v.u;
    unsigned int r = x + 0x7FFFu + ((x >> 16) & 1u);
    return (unsigned short)(r >> 16);
}

// Fast staging cvt: round-half-up (+0x8000) then pack two high-halves with
// one v_perm_b32. 3 VALU per pair -> staging stays MFMA-bound.
__device__ __forceinline__ unsigned int pack_bf2(float x, float y) {
    unsigned int a = __builtin_bit_cast(unsigned int, x) + 0x8000u;
    unsigned int b = __builtin_bit_cast(unsigned int, y) + 0x8000u;
    // v_perm_b32: src1 = bytes 0..3, src0 = bytes 4..7; result low16=a>>16, high16=b>>16
    return __builtin_amdgcn_perm(b, a, 0x07060302);
}
__device__ __forceinline__ u16x8 cvt8(float4 p, float4 q) {
    union { u16x8 v; unsigned int w[4]; } u;
    u.w[0] = pack_bf2(p.x, p.y);
    u.w[1] = pack_bf2(p.z, p.w);
    u.w[2] = pack_bf2(q.x, q.y);
    u.w[3] = pack_bf2(q.z, q.w);
    return u.v;
}

// ---------------- routing kernels ----------------

// cw[e*T + t] += rw[t,k] for each selected expert slot (dupes in top-k sum)
__global__ void cw_scatter(const int* __restrict__ sel,
                           const float* __restrict__ rw,
                           float* __restrict__ cw) {
    int i = blockIdx.x * blockDim.x + threadIdx.x;
    if (i < T_TOK * TOPK) {
        int t = i / TOPK;
        int e = sel[i];
        atomicAdd(&cw[e * T_TOK + t], rw[i]);
    }
}

// per-expert compact token lists: list[e*1024 + pos] = t  (order arbitrary)
__global__ void build_lists(const float* __restrict__ cw,
                            int* __restrict__ list,
                            int* __restrict__ count) {
    int i = blockIdx.x * blockDim.x + threadIdx.x;
    if (i < NE * T_TOK) {
        int e = i >> 10;
        float c = cw[i];
        if (c != 0.f) {
            int p = atomicAdd(&count[e], 1);
            list[(e << 10) + p] = i & 1023;
        }
    }
}

// ---------------- GEMM1: sparse fused gate+up+SwiGLU ----------------
// For expert e, gathered tokens: G = x_g @ w0e^T, U = x_g @ w1e^T (K=D=2048)
// hc[e*1024 + slot, f] = silu(G*s0)*(U*s1) * cw * s2   (bf16, compact slab)
// fp32 global -> in-register bf16 pack -> LDS. Tile 128x128, BK=64, 4 waves.
__global__ __launch_bounds__(256, 2)
void gemm1_kernel(const float* __restrict__ xf,   // [T, D] fp32
                  const float* __restrict__ w0,   // [E, DFF, D] fp32
                  const float* __restrict__ w1,   // [E, DFF, D] fp32
                  const float* __restrict__ cw,   // [E, T]
                  const int* __restrict__ list,   // [E, 1024]
                  const int* __restrict__ count,  // [E]
                  const float* __restrict__ s0,
                  const float* __restrict__ s1,
                  const float* __restrict__ s2,
                  unsigned short* __restrict__ hc) // [E*1024, DFF] compact
{
    const int tf = blockIdx.x, tile = blockIdx.y, e = blockIdx.z;
    const int n_e = count[e];
    const int base = tile * 128;
    if (base >= n_e) return;

    const int tid = threadIdx.x;
    const int lane = tid & 63, wid = tid >> 6;
    const int wm = wid >> 1, wn = wid & 1;
    const int quad = lane >> 4, l16 = lane & 15;

    __shared__ alignas(16) unsigned short sA [128 * 64];
    __shared__ alignas(16) unsigned short sB0[128 * 64];
    __shared__ alignas(16) unsigned short sB1[128 * 64];
    __shared__ int   slist[128];
    __shared__ float cws[128];

    if (tid < 128) {
        int idx = base + tid;
        int cl = idx < n_e ? idx : (n_e - 1);     // clamp padded rows to a valid token
        int tok = list[(e << 10) + cl];
        slist[tid] = tok;
        cws[tid] = (idx < n_e) ? cw[e * T_TOK + tok] : 0.f;  // padded rows -> 0
    }
    __syncthreads();

    int rowtok[4];
#pragma unroll
    for (int it = 0; it < 4; ++it) rowtok[it] = slist[it * 32 + (tid >> 3)];

    const float* b0_base = w0 + ((size_t)e * DFF + tf * 128) * D_DIM;
    const float* b1_base = w1 + ((size_t)e * DFF + tf * 128) * D_DIM;

    f32x4 accG[4][4], accU[4][4];
    const f32x4 zz = {0.f, 0.f, 0.f, 0.f};
#pragma unroll
    for (int mi = 0; mi < 4; ++mi)
#pragma unroll
        for (int ni = 0; ni < 4; ++ni) { accG[mi][ni] = zz; accU[mi][ni] = zz; }

    for (int k0 = 0; k0 < D_DIM; k0 += 64) {
        u16x8 rA[4], rB0[4], rB1[4];
#pragma unroll
        for (int it = 0; it < 4; ++it) {
            int c = it * 256 + tid;
            int row = c >> 3, col = c & 7;
            const float* ap = xf + (size_t)rowtok[it] * D_DIM + k0 + col * 8;
            float4 a0 = *(const float4*)ap, a1 = *(const float4*)(ap + 4);
            const float* bp0 = b0_base + (size_t)row * D_DIM + k0 + col * 8;
            float4 b00 = *(const float4*)bp0, b01 = *(const float4*)(bp0 + 4);
            const float* bp1 = b1_base + (size_t)row * D_DIM + k0 + col * 8;
            float4 b10 = *(const float4*)bp1, b11 = *(const float4*)(bp1 + 4);
            rA [it] = cvt8(a0, a1);
            rB0[it] = cvt8(b00, b01);
            rB1[it] = cvt8(b10, b11);
        }
        __syncthreads();   // previous K-step's compute done before LDS overwrite
#pragma unroll
        for (int it = 0; it < 4; ++it) {
            int c = it * 256 + tid;
            int row = c >> 3, col = c & 7;
            int cs = col ^ (row & 7);          // XOR swizzle
            *(u16x8*)(sA  + row * 64 + cs * 8) = rA [it];
            *(u16x8*)(sB0 + row * 64 + cs * 8) = rB0[it];
            *(u16x8*)(sB1 + row * 64 + cs * 8) = rB1[it];
        }
        __syncthreads();
#pragma unroll
        for (int kk = 0; kk < 2; ++kk) {
            bf16x8 af[4], b0f[4], b1f[4];
#pragma unroll
            for (int mi = 0; mi < 4; ++mi) {
                int row = wm * 64 + mi * 16 + l16;
                int cch = (kk * 4 + quad) ^ (row & 7);
                af[mi] = __builtin_bit_cast(bf16x8,
                         *(const u16x8*)(sA + row * 64 + cch * 8));
            }
#pragma unroll
            for (int ni = 0; ni < 4; ++ni) {
                int row = wn * 64 + ni * 16 + l16;
                int cch = (kk * 4 + quad) ^ (row & 7);
                b0f[ni] = __builtin_bit_cast(bf16x8,
                          *(const u16x8*)(sB0 + row * 64 + cch * 8));
                b1f[ni] = __builtin_bit_cast(bf16x8,
                          *(const u16x8*)(sB1 + row * 64 + cch * 8));
            }
#pragma unroll
            for (int mi = 0; mi < 4; ++mi)
#pragma unroll
                for (int ni = 0; ni < 4; ++ni) {
                    accG[mi][ni] = __builtin_amdgcn_mfma_f32_16x16x32_bf16(
                        af[mi], b0f[ni], accG[mi][ni], 0, 0, 0);
                    accU[mi][ni] = __builtin_amdgcn_mfma_f32_16x16x32_bf16(
                        af[mi], b1f[ni], accU[mi][ni], 0, 0, 0);
                }
        }
    }

    const float s0e = s0[e], s1e = s1[e], s2e = s2[e];
#pragma unroll
    for (int mi = 0; mi < 4; ++mi) {
#pragma unroll
        for (int reg = 0; reg < 4; ++reg) {
            int tl = wm * 64 + mi * 16 + quad * 4 + reg;   // C/D row = quad*4+reg
            float cwt = cws[tl] * s2e;                      // 0 for padded rows
            size_t slot = (size_t)((e << 10) + base + tl);
#pragma unroll
            for (int ni = 0; ni < 4; ++ni) {
                float g = accG[mi][ni][reg] * s0e;
                float u = accU[mi][ni][reg] * s1e;
                float h = g / (1.f + __expf(-g)) * u;      // silu(g)*u
                int fc = tf * 128 + wn * 64 + ni * 16 + l16;  // C/D col = lane&15
                hc[slot * DFF + fc] = f2bf(h * cwt);       // padded rows -> 0
            }
        }
    }
}

// ---------------- GEMM2: sparse down projection ----------------
// For expert e: y = hc_e @ w2e^T (K=DFF=1024), scatter-add into out (zeroed).
__global__ __launch_bounds__(256, 2)
void gemm2_kernel(const unsigned short* __restrict__ hc,  // [E*1024, DFF] bf16
                  const float* __restrict__ w2,           // [E, D, DFF] fp32
                  const int* __restrict__ list,
                  const int* __restrict__ count,
                  float* __restrict__ out)                // [T, D] (pre-zeroed)
{
    const int td = blockIdx.x, tile = blockIdx.y, e = blockIdx.z;
    const int n_e = count[e];
    const int base = tile * 128;
    if (base >= n_e) return;

    const int tid = threadIdx.x;
    const int lane = tid & 63, wid = tid >> 6;
    const int wm = wid >> 1, wn = wid & 1;
    const int quad = lane >> 4, l16 = lane & 15;

    __shared__ alignas(16) unsigned short sA[128 * 64];
    __shared__ alignas(16) unsigned short sB[128 * 64];
    __shared__ int slist[128];

    if (tid < 128) {
        int idx = base + tid;
        int cl = idx < n_e ? idx : (n_e - 1);
        slist[tid] = list[(e << 10) + cl];
    }
    __syncthreads();

    const unsigned short* a_base = hc + (size_t)((e << 10) + base) * DFF;
    const float* b_base = w2 + ((size_t)e * D_DIM + td * 128) * DFF;

    f32x4 acc[4][4];
    const f32x4 zz = {0.f, 0.f, 0.f, 0.f};
#pragma unroll
    for (int mi = 0; mi < 4; ++mi)
#pragma unroll
        for (int ni = 0; ni < 4; ++ni) acc[mi][ni] = zz;

    for (int k0 = 0; k0 < DFF; k0 += 64) {
        u16x8 rA[4], rB[4];
#pragma unroll
        for (int it = 0; it < 4; ++it) {
            int c = it * 256 + tid;
            int row = c >> 3, col = c & 7;
            rA[it] = *(const u16x8*)(a_base + (size_t)row * DFF + k0 + col * 8);
            const float* bp = b_base + (size_t)row * DFF + k0 + col * 8;
            float4 b0 = *(const float4*)bp, b1 = *(const float4*)(bp + 4);
            rB[it] = cvt8(b0, b1);
        }
        __syncthreads();
#pragma unroll
        for (int it = 0; it < 4; ++it) {
            int c = it * 256 + tid;
            int row = c >> 3, col = c & 7;
            int cs = col ^ (row & 7);
            *(u16x8*)(sA + row * 64 + cs * 8) = rA[it];
            *(u16x8*)(sB + row * 64 + cs * 8) = rB[it];
        }
        __syncthreads();
#pragma unroll
        for (int kk = 0; kk < 2; ++kk) {
            bf16x8 af[4], bfr[4];
#pragma unroll
            for (int mi = 0; mi < 4; ++mi) {
                int row = wm * 64 + mi * 16 + l16;
                int cch = (kk * 4 + quad) ^ (row & 7);
                af[mi] = __builtin_bit_cast(bf16x8,
                         *(const u16x8*)(sA + row * 64 + cch * 8));
            }
#pragma unroll
            for (int ni = 0; ni < 4; ++ni) {
                int row = wn * 64 + ni * 16 + l16;
                int cch = (kk * 4 + quad) ^ (row & 7);
                bfr[ni] = __builtin_bit_cast(bf16x8,
                          *(const u16x8*)(sB + row * 64 + cch * 8));
            }
#pragma unroll
            for (int mi = 0; mi < 4; ++mi)
#pragma unroll
                for (int ni = 0; ni < 4; ++ni)
                    acc[mi][ni] = __builtin_amdgcn_mfma_f32_16x16x32_bf16(
                        af[mi], bfr[ni], acc[mi][ni], 0, 0, 0);
        }
    }

#pragma unroll
    for (int mi = 0; mi < 4; ++mi)
#pragma unroll
        for (int reg = 0; reg < 4; ++reg) {
            int tl = wm * 64 + mi * 16 + quad * 4 + reg;
            if (base + tl < n_e) {
                int tok = slist[tl];
                float* orow = out + (size_t)tok * D_DIM;
#pragma unroll
                for (int ni = 0; ni < 4; ++ni) {
                    int d = td * 128 + wn * 64 + ni * 16 + l16;
                    atomicAdd(orow + d, acc[mi][ni][reg]);
                }
            }
        }
}

// ---------------- launch ----------------

extern "C" void kernel_launch(void* const* d_in, const int* in_sizes, int n_in,
                              void* d_out, int out_size, void* d_ws, size_t ws_size,
                              hipStream_t stream) {
    const float* x  = (const float*)d_in[0];
    const float* w0 = (const float*)d_in[1];
    const float* w1 = (const float*)d_in[2];
    const float* w2 = (const float*)d_in[3];
    const float* s0 = (const float*)d_in[4];
    const float* s1 = (const float*)d_in[5];
    const float* s2 = (const float*)d_in[6];
    const int*   sel = (const int*)d_in[7];
    const float* rw = (const float*)d_in[8];
    float* out = (float*)d_out;

    char* ws = (char*)d_ws;
    // layout: hc slab 32 MB | list 64 KB | cw 64 KB | count 64 B
    constexpr size_t HC_OFF    = 0;
    constexpr size_t LIST_OFF  = 33554432ull;
    constexpr size_t CW_OFF    = LIST_OFF + 65536ull;
    constexpr size_t COUNT_OFF = CW_OFF + 65536ull;
    unsigned short* hc    = (unsigned short*)(ws + HC_OFF);
    int*            list  = (int*)           (ws + LIST_OFF);
    float*          cw    = (float*)         (ws + CW_OFF);
    int*            count = (int*)           (ws + COUNT_OFF);

    // 1. routing: cw[E,T], per-expert token lists (cw+count zeroed in one memset)
    hipMemsetAsync(cw, 0, 65536 + 256, stream);
    cw_scatter<<<(T_TOK * TOPK + 255) / 256, 256, 0, stream>>>(sel, rw, cw);
    build_lists<<<(NE * T_TOK + 255) / 256, 256, 0, stream>>>(cw, list, count);

    // 2. zero output (gemm2 scatter-adds into it)
    hipMemsetAsync(out, 0, (size_t)T_TOK * D_DIM * sizeof(float), stream);

    // 3. sparse fused gate/up/SwiGLU -> compact hc (cw*s2 folded in)
    gemm1_kernel<<<dim3(DFF / 128, T_TOK / 128, NE), 256, 0, stream>>>(
        x, w0, w1, cw, list, count, s0, s1, s2, hc);

    // 4. sparse down projection, scatter-add into out
    gemm2_kernel<<<dim3(D_DIM / 128, T_TOK / 128, NE), 256, 0, stream>>>(
        hc, w2, list, count, out);
}

// Round 3
// 534.836 us; speedup vs baseline: 1.1836x; 1.0445x over previous
//
#include <hip/hip_runtime.h>
#include <hip/hip_bf16.h>
#include <stdint.h>

// Problem constants
#define T_TOK 1024
#define D_DIM 2048
#define DFF   1024
#define NE    16
#define TOPK  6

typedef float f32x4 __attribute__((ext_vector_type(4)));
typedef __bf16 bf16x8 __attribute__((ext_vector_type(8)));
typedef unsigned short u16x8 __attribute__((ext_vector_type(8)));

// RNE float -> bf16 (finite inputs only)
__device__ __forceinline__ unsigned short f2bf(float f) {
    union { float f; unsigned int u; } v; v.f = f;
    unsigned int x = v.u;
    unsigned int r = x + 0x7FFFu + ((x >> 16) & 1u);
    return (unsigned short)(r >> 16);
}

// ---------------- streaming fp32 -> bf16 conversion ----------------
__global__ void cvt_f32_bf16(const float* __restrict__ src,
                             unsigned short* __restrict__ dst, int n4) {
    int i = blockIdx.x * blockDim.x + threadIdx.x;
    int stride = gridDim.x * blockDim.x;
    for (; i < n4; i += stride) {
        float4 v = ((const float4*)src)[i];
        ushort4 o;
        o.x = f2bf(v.x); o.y = f2bf(v.y); o.z = f2bf(v.z); o.w = f2bf(v.w);
        ((ushort4*)dst)[i] = o;
    }
}

// ---------------- routing: single-block, LDS, no global atomics ----------------
// cw[e,t] = sum of rw[t,k] over slots with sel[t,k]==e; per-expert compact
// token lists + counts. Column t is owned by thread t -> no atomics for cw.
__global__ __launch_bounds__(1024)
void routing_kernel(const int* __restrict__ sel,    // [T, K]
                    const float* __restrict__ rw,   // [T, K]
                    float* __restrict__ cw,         // [E, T]
                    int* __restrict__ list,         // [E, 1024]
                    int* __restrict__ count) {      // [E]
    __shared__ float scw[NE * T_TOK];   // 64 KB
    __shared__ int scount[NE];
    const int t = threadIdx.x;
#pragma unroll
    for (int e = 0; e < NE; ++e) scw[e * T_TOK + t] = 0.f;
    if (t < NE) scount[t] = 0;
    __syncthreads();
#pragma unroll
    for (int k = 0; k < TOPK; ++k) {
        int e = sel[t * TOPK + k];
        scw[e * T_TOK + t] += rw[t * TOPK + k];   // owner-thread RMW, safe
    }
    __syncthreads();
#pragma unroll
    for (int e = 0; e < NE; ++e) {
        float c = scw[e * T_TOK + t];
        cw[e * T_TOK + t] = c;
        if (c != 0.f) {
            int p = atomicAdd(&scount[e], 1);     // LDS atomic
            list[(e << 10) + p] = t;
        }
    }
    __syncthreads();
    if (t < NE) count[t] = scount[t];
}

// ---------------- GEMM1: sparse fused gate+up+SwiGLU (bf16) ----------------
// For expert e, gathered tokens: G = x_g @ w0e^T, U = x_g @ w1e^T (K=D=2048)
// hc[e*1024 + slot, f] = silu(G*s0)*(U*s1) * cw * s2   (bf16, compact slab)
// Tile 128x128, BK=64, 4 waves (2x2), dual accumulators, XOR-swizzled LDS.
__global__ __launch_bounds__(256, 2)
void gemm1_kernel(const unsigned short* __restrict__ xb,   // [T, D] bf16
                  const unsigned short* __restrict__ wb0,  // [E, DFF, D] bf16
                  const unsigned short* __restrict__ wb1,  // [E, DFF, D] bf16
                  const float* __restrict__ cw,            // [E, T]
                  const int* __restrict__ list,            // [E, 1024]
                  const int* __restrict__ count,           // [E]
                  const float* __restrict__ s0,
                  const float* __restrict__ s1,
                  const float* __restrict__ s2,
                  unsigned short* __restrict__ hc)         // [E*1024, DFF]
{
    const int tf = blockIdx.x, tile = blockIdx.y, e = blockIdx.z;
    const int n_e = count[e];
    const int base = tile * 128;
    if (base >= n_e) return;

    const int tid = threadIdx.x;
    const int lane = tid & 63, wid = tid >> 6;
    const int wm = wid >> 1, wn = wid & 1;
    const int quad = lane >> 4, l16 = lane & 15;

    __shared__ alignas(16) unsigned short sA [128 * 64];
    __shared__ alignas(16) unsigned short sB0[128 * 64];
    __shared__ alignas(16) unsigned short sB1[128 * 64];
    __shared__ int   slist[128];
    __shared__ float cws[128];

    if (tid < 128) {
        int idx = base + tid;
        int cl = idx < n_e ? idx : (n_e - 1);     // clamp pads to a valid token
        int tok = list[(e << 10) + cl];
        slist[tid] = tok;
        cws[tid] = (idx < n_e) ? cw[e * T_TOK + tok] : 0.f;  // pads -> 0
    }
    __syncthreads();

    int rowtok[4];
#pragma unroll
    for (int it = 0; it < 4; ++it) rowtok[it] = slist[it * 32 + (tid >> 3)];

    const unsigned short* b0_base = wb0 + ((size_t)e * DFF + tf * 128) * D_DIM;
    const unsigned short* b1_base = wb1 + ((size_t)e * DFF + tf * 128) * D_DIM;

    f32x4 accG[4][4], accU[4][4];
    const f32x4 zz = {0.f, 0.f, 0.f, 0.f};
#pragma unroll
    for (int mi = 0; mi < 4; ++mi)
#pragma unroll
        for (int ni = 0; ni < 4; ++ni) { accG[mi][ni] = zz; accU[mi][ni] = zz; }

    for (int k0 = 0; k0 < D_DIM; k0 += 64) {
        u16x8 rA[4], rB0[4], rB1[4];
#pragma unroll
        for (int it = 0; it < 4; ++it) {
            int c = it * 256 + tid;
            int row = c >> 3, col = c & 7;
            rA [it] = *(const u16x8*)(xb + (size_t)rowtok[it] * D_DIM + k0 + col * 8);
            rB0[it] = *(const u16x8*)(b0_base + (size_t)row * D_DIM + k0 + col * 8);
            rB1[it] = *(const u16x8*)(b1_base + (size_t)row * D_DIM + k0 + col * 8);
        }
        __syncthreads();   // prev K-step compute done before LDS overwrite
#pragma unroll
        for (int it = 0; it < 4; ++it) {
            int c = it * 256 + tid;
            int row = c >> 3, col = c & 7;
            int cs = col ^ (row & 7);          // XOR swizzle
            *(u16x8*)(sA  + row * 64 + cs * 8) = rA [it];
            *(u16x8*)(sB0 + row * 64 + cs * 8) = rB0[it];
            *(u16x8*)(sB1 + row * 64 + cs * 8) = rB1[it];
        }
        __syncthreads();
#pragma unroll
        for (int kk = 0; kk < 2; ++kk) {
            bf16x8 af[4], b0f[4], b1f[4];
#pragma unroll
            for (int mi = 0; mi < 4; ++mi) {
                int row = wm * 64 + mi * 16 + l16;
                int cch = (kk * 4 + quad) ^ (row & 7);
                af[mi] = __builtin_bit_cast(bf16x8,
                         *(const u16x8*)(sA + row * 64 + cch * 8));
            }
#pragma unroll
            for (int ni = 0; ni < 4; ++ni) {
                int row = wn * 64 + ni * 16 + l16;
                int cch = (kk * 4 + quad) ^ (row & 7);
                b0f[ni] = __builtin_bit_cast(bf16x8,
                          *(const u16x8*)(sB0 + row * 64 + cch * 8));
                b1f[ni] = __builtin_bit_cast(bf16x8,
                          *(const u16x8*)(sB1 + row * 64 + cch * 8));
            }
#pragma unroll
            for (int mi = 0; mi < 4; ++mi)
#pragma unroll
                for (int ni = 0; ni < 4; ++ni) {
                    accG[mi][ni] = __builtin_amdgcn_mfma_f32_16x16x32_bf16(
                        af[mi], b0f[ni], accG[mi][ni], 0, 0, 0);
                    accU[mi][ni] = __builtin_amdgcn_mfma_f32_16x16x32_bf16(
                        af[mi], b1f[ni], accU[mi][ni], 0, 0, 0);
                }
        }
    }

    const float s0e = s0[e], s1e = s1[e], s2e = s2[e];
#pragma unroll
    for (int mi = 0; mi < 4; ++mi) {
#pragma unroll
        for (int reg = 0; reg < 4; ++reg) {
            int tl = wm * 64 + mi * 16 + quad * 4 + reg;   // C/D row = quad*4+reg
            float cwt = cws[tl] * s2e;                      // 0 for padded rows
            size_t slot = (size_t)((e << 10) + base + tl);
#pragma unroll
            for (int ni = 0; ni < 4; ++ni) {
                float g = accG[mi][ni][reg] * s0e;
                float u = accU[mi][ni][reg] * s1e;
                float h = g / (1.f + __expf(-g)) * u;      // silu(g)*u
                int fc = tf * 128 + wn * 64 + ni * 16 + l16;  // C/D col = lane&15
                hc[slot * DFF + fc] = f2bf(h * cwt);
            }
        }
    }
}

// ---------------- GEMM2: sparse down projection (bf16) ----------------
// For expert e: y = hc_e @ w2e^T (K=DFF=1024), scatter-add into out (zeroed).
__global__ __launch_bounds__(256, 2)
void gemm2_kernel(const unsigned short* __restrict__ hc,   // [E*1024, DFF] bf16
                  const unsigned short* __restrict__ wb2,  // [E, D, DFF] bf16
                  const int* __restrict__ list,
                  const int* __restrict__ count,
                  float* __restrict__ out)                 // [T, D] pre-zeroed
{
    const int td = blockIdx.x, tile = blockIdx.y, e = blockIdx.z;
    const int n_e = count[e];
    const int base = tile * 128;
    if (base >= n_e) return;

    const int tid = threadIdx.x;
    const int lane = tid & 63, wid = tid >> 6;
    const int wm = wid >> 1, wn = wid & 1;
    const int quad = lane >> 4, l16 = lane & 15;

    __shared__ alignas(16) unsigned short sA[128 * 64];
    __shared__ alignas(16) unsigned short sB[128 * 64];
    __shared__ int slist[128];

    if (tid < 128) {
        int idx = base + tid;
        int cl = idx < n_e ? idx : (n_e - 1);
        slist[tid] = list[(e << 10) + cl];
    }
    __syncthreads();

    const unsigned short* a_base = hc + (size_t)((e << 10) + base) * DFF;
    const unsigned short* b_base = wb2 + ((size_t)e * D_DIM + td * 128) * DFF;

    f32x4 acc[4][4];
    const f32x4 zz = {0.f, 0.f, 0.f, 0.f};
#pragma unroll
    for (int mi = 0; mi < 4; ++mi)
#pragma unroll
        for (int ni = 0; ni < 4; ++ni) acc[mi][ni] = zz;

    for (int k0 = 0; k0 < DFF; k0 += 64) {
        u16x8 rA[4], rB[4];
#pragma unroll
        for (int it = 0; it < 4; ++it) {
            int c = it * 256 + tid;
            int row = c >> 3, col = c & 7;
            rA[it] = *(const u16x8*)(a_base + (size_t)row * DFF + k0 + col * 8);
            rB[it] = *(const u16x8*)(b_base + (size_t)row * DFF + k0 + col * 8);
        }
        __syncthreads();
#pragma unroll
        for (int it = 0; it < 4; ++it) {
            int c = it * 256 + tid;
            int row = c >> 3, col = c & 7;
            int cs = col ^ (row & 7);
            *(u16x8*)(sA + row * 64 + cs * 8) = rA[it];
            *(u16x8*)(sB + row * 64 + cs * 8) = rB[it];
        }
        __syncthreads();
#pragma unroll
        for (int kk = 0; kk < 2; ++kk) {
            bf16x8 af[4], bfr[4];
#pragma unroll
            for (int mi = 0; mi < 4; ++mi) {
                int row = wm * 64 + mi * 16 + l16;
                int cch = (kk * 4 + quad) ^ (row & 7);
                af[mi] = __builtin_bit_cast(bf16x8,
                         *(const u16x8*)(sA + row * 64 + cch * 8));
            }
#pragma unroll
            for (int ni = 0; ni < 4; ++ni) {
                int row = wn * 64 + ni * 16 + l16;
                int cch = (kk * 4 + quad) ^ (row & 7);
                bfr[ni] = __builtin_bit_cast(bf16x8,
                          *(const u16x8*)(sB + row * 64 + cch * 8));
            }
#pragma unroll
            for (int mi = 0; mi < 4; ++mi)
#pragma unroll
                for (int ni = 0; ni < 4; ++ni)
                    acc[mi][ni] = __builtin_amdgcn_mfma_f32_16x16x32_bf16(
                        af[mi], bfr[ni], acc[mi][ni], 0, 0, 0);
        }
    }

#pragma unroll
    for (int mi = 0; mi < 4; ++mi)
#pragma unroll
        for (int reg = 0; reg < 4; ++reg) {
            int tl = wm * 64 + mi * 16 + quad * 4 + reg;
            if (base + tl < n_e) {
                int tok = slist[tl];
                float* orow = out + (size_t)tok * D_DIM;
#pragma unroll
                for (int ni = 0; ni < 4; ++ni) {
                    int d = td * 128 + wn * 64 + ni * 16 + l16;
                    atomicAdd(orow + d, acc[mi][ni][reg]);
                }
            }
        }
}

// ---------------- launch ----------------

extern "C" void kernel_launch(void* const* d_in, const int* in_sizes, int n_in,
                              void* d_out, int out_size, void* d_ws, size_t ws_size,
                              hipStream_t stream) {
    const float* x  = (const float*)d_in[0];
    const float* w0 = (const float*)d_in[1];
    const float* w1 = (const float*)d_in[2];
    const float* w2 = (const float*)d_in[3];
    const float* s0 = (const float*)d_in[4];
    const float* s1 = (const float*)d_in[5];
    const float* s2 = (const float*)d_in[6];
    const int*   sel = (const int*)d_in[7];
    const float* rw = (const float*)d_in[8];
    float* out = (float*)d_out;

    char* ws = (char*)d_ws;
    // layout (peak ~172 MB; w2b reuses w0b region after gemm1):
    constexpr size_t W0B_OFF   = 0;                     // 67,108,864 (later W2B)
    constexpr size_t W1B_OFF   = 67108864ull;           // 67,108,864
    constexpr size_t XB_OFF    = 134217728ull;          //  4,194,304
    constexpr size_t HC_OFF    = 138412032ull;          // 33,554,432
    constexpr size_t LIST_OFF  = 171966464ull;          //     65,536
    constexpr size_t CW_OFF    = LIST_OFF + 65536ull;   //     65,536
    constexpr size_t COUNT_OFF = CW_OFF + 65536ull;     //         64
    unsigned short* w0b   = (unsigned short*)(ws + W0B_OFF);
    unsigned short* w1b   = (unsigned short*)(ws + W1B_OFF);
    unsigned short* w2b   = (unsigned short*)(ws + W0B_OFF);  // reuse
    unsigned short* xb    = (unsigned short*)(ws + XB_OFF);
    unsigned short* hc    = (unsigned short*)(ws + HC_OFF);
    int*            list  = (int*)           (ws + LIST_OFF);
    float*          cw    = (float*)         (ws + CW_OFF);
    int*            count = (int*)           (ws + COUNT_OFF);

    // 1. routing (single block; builds cw, list, count)
    routing_kernel<<<1, 1024, 0, stream>>>(sel, rw, cw, list, count);

    // 2. zero output (gemm2 scatter-adds into it)
    hipMemsetAsync(out, 0, (size_t)T_TOK * D_DIM * sizeof(float), stream);

    // 3. stream-convert gemm1 inputs to bf16
    cvt_f32_bf16<<<4096, 256, 0, stream>>>(w0, w0b, NE * DFF * D_DIM / 4);
    cvt_f32_bf16<<<4096, 256, 0, stream>>>(w1, w1b, NE * DFF * D_DIM / 4);
    cvt_f32_bf16<<<1024, 256, 0, stream>>>(x,  xb,  T_TOK * D_DIM / 4);

    // 4. sparse fused gate/up/SwiGLU -> compact hc (cw*s2 folded in)
    gemm1_kernel<<<dim3(DFF / 128, T_TOK / 128, NE), 256, 0, stream>>>(
        xb, w0b, w1b, cw, list, count, s0, s1, s2, hc);

    // 5. convert w2 (into the now-dead w0b region)
    cvt_f32_bf16<<<4096, 256, 0, stream>>>(w2, w2b, NE * D_DIM * DFF / 4);

    // 6. sparse down projection, scatter-add into out
    gemm2_kernel<<<dim3(D_DIM / 128, T_TOK / 128, NE), 256, 0, stream>>>(
        hc, w2b, list, count, out);
}